// Round 19
// baseline (171.013 us; speedup 1.0000x reference)
//
#include <hip/hip_runtime.h>
#include <hip/hip_bf16.h>

#define NLOG 16
#define NN 65536
#define KK 9
#define FF 32
#define OO 64
#define DD 288            // K*F
#define WSTR 296          // fallback path only
#define CHUNK 128         // points per block-chunk (8 waves x 16)
#define THREADS 512
#define GRID 1024         // GRID*CHUNK = 2*NN -> vertex round-invariant
#define ROUNDS 4          // NCHUNKS / GRID
#define PTHREADS 256      // precvt block size
#define NBLOCKS 1024      // fallback grid
#define TOTALP (8 * NN)           // 524288
#define NCHUNKS (TOTALP / CHUNK)  // 4096
#define RA_STRIDE 72              // shorts/point: 9 T-ROWS x 8 bf16 (k=0..7)
#define RB_STRIDE 10              // shorts/point: k=8 column over t, +1 pad
#define NB_STRIDE 10              // u16 indices/point: 9 + 1 pad
#define AJW 88                    // LDS adj stride (shorts): 72 + 9 + 7 pad

// fused pre-kernel block ranges (PTHREADS=256)
#define XB (TOTALP * FF / 8 / PTHREADS)  // 8192
#define AB (NN * KK / PTHREADS)          // 2304
#define NB (TOTALP / PTHREADS)           // 2048
#define WB (OO * DD / PTHREADS)          // 72

typedef float f32x4 __attribute__((ext_vector_type(4)));
typedef float f32x2 __attribute__((ext_vector_type(2)));
typedef unsigned int u32x4 __attribute__((ext_vector_type(4)));
typedef short s16x8 __attribute__((ext_vector_type(8)));
typedef short s16x4 __attribute__((ext_vector_type(4)));

static __device__ __forceinline__ short f2bf(float f) {
    union { __hip_bfloat16 h; short s; } u;
    u.h = __float2bfloat16(f);
    return u.s;
}

// exact bf16->f32
static __device__ __forceinline__ void bf2f2(unsigned int p, float& lo, float& hi) {
    union { unsigned int u; float f; } a, b;
    a.u = p << 16;
    b.u = p & 0xFFFF0000u;
    lo = a.f; hi = b.f;
}
static __device__ __forceinline__ float bf1(unsigned short s) {
    union { unsigned int u; float f; } a;
    a.u = ((unsigned int)s) << 16;
    return a.f;
}

// elu(x) = max(x, exp(min(x,0))-1)
static __device__ __forceinline__ float elu1(float x) {
    return fmaxf(x, __expf(fminf(x, 0.f)) - 1.f);
}

// ---- fused pre-kernel: xcvt | adjcvt(t-major) | ncvt | wcvt ----
__global__ __launch_bounds__(PTHREADS) void precvt(
    const float* __restrict__ x, unsigned short* __restrict__ xbf,
    const float* __restrict__ v, const float* __restrict__ aw,
    unsigned short* __restrict__ recA, unsigned short* __restrict__ recB,
    const int* __restrict__ nbr, unsigned short* __restrict__ nb16,
    const float* __restrict__ W, unsigned short* __restrict__ wbf)
{
    const int bid = blockIdx.x;
    if (bid < XB) {
        const size_t i = ((size_t)bid * PTHREADS + threadIdx.x) * 8;
        const f32x4 a = *(const f32x4*)(x + i);
        const f32x4 b = *(const f32x4*)(x + i + 4);
        s16x8 p;
        p[0] = f2bf(a.x); p[1] = f2bf(a.y); p[2] = f2bf(a.z); p[3] = f2bf(a.w);
        p[4] = f2bf(b.x); p[5] = f2bf(b.y); p[6] = f2bf(b.z); p[7] = f2bf(b.w);
        *(s16x8*)(xbf + i) = p;
    } else if (bid < XB + AB) {
        // adjacency -> packed bf16, t-major: recA[n][t][k=0..7], recB[n][t]=k8
        const int e = (bid - XB) * PTHREADS + threadIdx.x;   // over NN*KK
        const int n = e / KK;
        const int t = e - n * KK;
        const float* vr = v + n * 8;
        short o[8];
        float s8 = 0.f;
        #pragma unroll
        for (int k = 0; k < KK; ++k) {
            float s = 0.f;
            #pragma unroll
            for (int si = 0; si < 8; ++si)
                s += vr[si] * aw[si * 81 + k * 9 + t];
            if (k < 8) o[k] = f2bf(s); else s8 = s;
        }
        *(s16x8*)(recA + (size_t)n * RA_STRIDE + t * 8) = *(s16x8*)o;
        recB[(size_t)n * RB_STRIDE + t] = (unsigned short)f2bf(s8);
        if (t == 0) recB[(size_t)n * RB_STRIDE + 9] = 0;
    } else if (bid < XB + AB + NB) {
        const int p = (bid - XB - AB) * PTHREADS + threadIdx.x;  // over TOTALP
        const int* s = nbr + (size_t)p * KK;
        int r[KK];
        #pragma unroll
        for (int k = 0; k < KK; ++k) r[k] = s[k];
        unsigned int* d = (unsigned int*)(nb16 + (size_t)p * NB_STRIDE);
        #pragma unroll
        for (int j = 0; j < 4; ++j)
            d[j] = ((unsigned)r[2*j] & 0xFFFFu) | ((unsigned)r[2*j+1] << 16);
        d[4] = (unsigned)r[8] & 0xFFFFu;
    } else {
        // W -> bf16 lane-linear fragment layout (conflict-free wave reads)
        const int i = (bid - XB - AB - NB) * PTHREADS + threadIdx.x; // < 18432
        const int j     = i & 7;
        const int lane  = (i >> 3) & 63;
        const int tl    = i >> 9;          // t*4 + ot
        const int t     = tl >> 2;
        const int ot    = tl & 3;
        const int o     = ot * 16 + (lane & 15);
        const int d     = t * FF + (lane >> 4) * 8 + j;
        wbf[i] = (unsigned short)f2bf(W[o * DD + d]);
    }
}

// ======== main kernel: R16 + 1-deep cross-chunk gather prefetch ==========
// R16 (best, main 111us): VALUBusy 60%, MfmaUtil 7%, HBM 37%, occ 22% ->
// no pipe saturated = un-hidden gather latency. R9's prefetch spilled at
// VGPR 128 (adjacency in regs then); R18 baseline is 68 VGPR with adj in
// LDS -> a second PACKED gather buffer (36) + indices (5) fits (~110).
// Pipeline: issue chunk r+1's 9 gathers BEFORE computing chunk r.
//  * lane-linear W in LDS (conflict-free), AJ staged once (round-invariant),
//    bf16 x gather, u16 nbr, swapped MFMA, f32x4 stores, no nt, one barrier.
//  * No asm pins (R18: neutral-negative). t-loop re-unpack accepted (R17/R18:
//    3 attempts to remove it all failed; it is not the binding term).

#define LOADNBR(rw, rr)                                                     \
{                                                                           \
    const size_t P_ = (size_t)(blockIdx.x + (rr) * GRID) * CHUNK + pl;      \
    const unsigned int* np_ = (const unsigned int*)(nb16 + P_ * NB_STRIDE); \
    const unsigned int w0 = np_[0], w1 = np_[1], w2 = np_[2];               \
    const unsigned int w3 = np_[3], w4 = np_[4];                            \
    rw[0] = w0 & 0xFFFF; rw[1] = w0 >> 16;                                  \
    rw[2] = w1 & 0xFFFF; rw[3] = w1 >> 16;                                  \
    rw[4] = w2 & 0xFFFF; rw[5] = w2 >> 16;                                  \
    rw[6] = w3 & 0xFFFF; rw[7] = w3 >> 16;                                  \
    rw[8] = w4 & 0xFFFF;                                                    \
}

#define GATHER(gp, rw, rr)                                                  \
{                                                                           \
    const size_t P_ = (size_t)(blockIdx.x + (rr) * GRID) * CHUNK + pl;      \
    const unsigned short* xb_ = xbf + ((P_ >> NLOG) << NLOG) * FF + fo;     \
    _Pragma("unroll")                                                       \
    for (int k_ = 0; k_ < KK; ++k_)                                         \
        gp[k_] = *(const u32x4*)(xb_ + (size_t)rw[k_] * FF);                \
}

#define COMPUTE(gp, rr)                                                     \
{                                                                           \
    const size_t P_ = (size_t)(blockIdx.x + (rr) * GRID) * CHUNK + pl;      \
    f32x2 G2[KK][4];                                                        \
    _Pragma("unroll")                                                       \
    for (int k_ = 0; k_ < KK; ++k_) {                                       \
        float l0,h0,l1,h1,l2,h2,l3,h3;                                      \
        bf2f2(gp[k_].x, l0, h0);                                            \
        bf2f2(gp[k_].y, l1, h1);                                            \
        bf2f2(gp[k_].z, l2, h2);                                            \
        bf2f2(gp[k_].w, l3, h3);                                            \
        G2[k_][0] = f32x2{l0, h0};                                          \
        G2[k_][1] = f32x2{l1, h1};                                          \
        G2[k_][2] = f32x2{l2, h2};                                          \
        G2[k_][3] = f32x2{l3, h3};                                          \
    }                                                                       \
    f32x4 acc0 = {0,0,0,0}, acc1 = {0,0,0,0};                               \
    f32x4 acc2 = {0,0,0,0}, acc3 = {0,0,0,0};                               \
    _Pragma("unroll 1")                                                     \
    for (int t_ = 0; t_ < KK; ++t_) {                                       \
        float a_[KK];                                                       \
        {                                                                   \
            const u32x4 qv_ = *(const u32x4*)(ajp + t_ * 8);                \
            bf2f2(qv_.x, a_[0], a_[1]);                                     \
            bf2f2(qv_.y, a_[2], a_[3]);                                     \
            bf2f2(qv_.z, a_[4], a_[5]);                                     \
            bf2f2(qv_.w, a_[6], a_[7]);                                     \
            a_[8] = bf1(ajp[RA_STRIDE + t_]);                               \
        }                                                                   \
        f32x2 xn2_[4] = {{0,0},{0,0},{0,0},{0,0}};                          \
        _Pragma("unroll")                                                   \
        for (int k_ = 0; k_ < KK; ++k_) {                                   \
            const f32x2 ak_ = {a_[k_], a_[k_]};                             \
            _Pragma("unroll")                                               \
            for (int i_ = 0; i_ < 4; ++i_) xn2_[i_] += G2[k_][i_] * ak_;    \
        }                                                                   \
        s16x8 af_;                                                          \
        _Pragma("unroll")                                                   \
        for (int i_ = 0; i_ < 4; ++i_) {                                    \
            af_[2*i_]   = f2bf(elu1(xn2_[i_].x));                           \
            af_[2*i_+1] = f2bf(elu1(xn2_[i_].y));                           \
        }                                                                   \
        const s16x8 b0_ = *(const s16x8*)(wl + (t_ * 4 + 0) * 512);         \
        const s16x8 b1_ = *(const s16x8*)(wl + (t_ * 4 + 1) * 512);         \
        const s16x8 b2_ = *(const s16x8*)(wl + (t_ * 4 + 2) * 512);         \
        const s16x8 b3_ = *(const s16x8*)(wl + (t_ * 4 + 3) * 512);         \
        acc0 = __builtin_amdgcn_mfma_f32_16x16x32_bf16(b0_, af_, acc0,0,0,0);\
        acc1 = __builtin_amdgcn_mfma_f32_16x16x32_bf16(b1_, af_, acc1,0,0,0);\
        acc2 = __builtin_amdgcn_mfma_f32_16x16x32_bf16(b2_, af_, acc2,0,0,0);\
        acc3 = __builtin_amdgcn_mfma_f32_16x16x32_bf16(b3_, af_, acc3,0,0,0);\
    }                                                                       \
    const bool zp_ = ((P_ & (NN - 1)) == (NN - 1));                         \
    float* orow_ = out + P_ * OO + fg * 4;                                  \
    _Pragma("unroll")                                                       \
    for (int ot_ = 0; ot_ < 4; ++ot_) {                                     \
        const f32x4 av_ = (ot_==0)?acc0:(ot_==1)?acc1:(ot_==2)?acc2:acc3;   \
        const f32x4 bv_ = *(const f32x4*)(bias + ot_ * 16 + fg * 4);        \
        f32x4 rr_;                                                          \
        _Pragma("unroll")                                                   \
        for (int j_ = 0; j_ < 4; ++j_)                                      \
            rr_[j_] = zp_ ? 0.f : elu1(av_[j_] + bv_[j_]);                  \
        *(f32x4*)(orow_ + ot_ * 16) = rr_;                                  \
    }                                                                       \
}

__global__ __launch_bounds__(THREADS, 2) void paiconv_main(
    const unsigned short* __restrict__ xbf,
    const unsigned short* __restrict__ nb16,
    const unsigned short* __restrict__ recA,
    const unsigned short* __restrict__ recB,
    const unsigned short* __restrict__ wbf,
    const float* __restrict__ bias,
    float* __restrict__ out)
{
    __shared__ short Wl[OO * DD];                // 36864 B, lane-linear
    __shared__ unsigned short AJ[CHUNK * AJW];   // 22528 B -> 59392 B total

    const int tid  = threadIdx.x;
    const int lane = tid & 63;
    const int wid  = tid >> 6;        // 0..7
    const int l15  = lane & 15;       // point within 16-tile (B-col)
    const int fg   = lane >> 4;       // octet group
    const int fo   = fg * 8;          // f offset (shorts)
    const int pl   = wid * 16 + l15;  // point within chunk (0..127)

    // ---- stage W (already permuted in global) linearly: conflict-free ----
    for (int e = tid; e < OO * DD / 8; e += THREADS) {
        const u32x4 r = *(const u32x4*)(wbf + (size_t)e * 8);
        *(u32x4*)(&Wl[e * 8]) = r;
    }
    // ---- stage adjacency (t-major) for the 128 round-invariant vertices --
    {
        const int vbase = (blockIdx.x * CHUNK) & (NN - 1);
        for (int e = tid; e < CHUNK * KK; e += THREADS) {
            const int p = e / KK;
            const int t = e - p * KK;
            const u32x4 r = *(const u32x4*)(recA + (size_t)(vbase + p) * RA_STRIDE + t * 8);
            *(u32x4*)(&AJ[p * AJW + t * 8]) = r;
        }
        if (tid < CHUNK) {
            #pragma unroll
            for (int t = 0; t < KK; ++t)
                AJ[tid * AJW + RA_STRIDE + t] =
                    recB[(size_t)(vbase + tid) * RB_STRIDE + t];
        }
    }
    __syncthreads();                    // only barrier in the kernel

    const unsigned short* ajp = &AJ[pl * AJW];
    const short* wl = &Wl[lane * 8];    // wave-linear base; imm offsets

    // ---- 1-deep software pipeline over the 4 rounds ----
    int rows0[KK], rows1[KK];
    u32x4 g0[KK], g1[KK];

    LOADNBR(rows0, 0);
    GATHER(g0, rows0, 0);               // prologue: one exposed gather
    LOADNBR(rows1, 1);

    #pragma unroll 1
    for (int rp = 0; rp < ROUNDS / 2; ++rp) {
        const int r0 = 2 * rp, r1 = 2 * rp + 1;
        GATHER(g1, rows1, r1);                 // in flight over COMPUTE(g0)
        if (rp < ROUNDS / 2 - 1) LOADNBR(rows0, r0 + 2);
        COMPUTE(g0, r0);
        if (rp < ROUNDS / 2 - 1) {
            GATHER(g0, rows0, r0 + 2);         // in flight over COMPUTE(g1)
            LOADNBR(rows1, r1 + 2);
        }
        COMPUTE(g1, r1);
    }
}

// =============== fallback (no-ws) kernel: R8 f32 path (256 thr) ==========
__global__ __launch_bounds__(PTHREADS, 2) void paiconv_fb(
    const float* __restrict__ x,
    const int* __restrict__ nbr,
    const float* __restrict__ v,
    const float* __restrict__ aw,
    const float* __restrict__ W,
    const float* __restrict__ bias,
    float* __restrict__ out)
{
    __shared__ short Wl[OO * WSTR];
    __shared__ float BL[OO];
    const int tid = threadIdx.x;
    for (int e = tid; e < OO * DD / 4; e += PTHREADS) {
        int o = e / 72;
        int d4 = (e - o * 72) * 4;
        const f32x4 wv = *(const f32x4*)(W + o * DD + d4);
        s16x4 p;
        p.x = f2bf(wv.x); p.y = f2bf(wv.y); p.z = f2bf(wv.z); p.w = f2bf(wv.w);
        *(s16x4*)(&Wl[o * WSTR + d4]) = p;
    }
    if (tid < OO) BL[tid] = bias[tid];
    __syncthreads();

    const int lane = tid & 63;
    const int wid  = tid >> 6;
    const int l15  = lane & 15;
    const int fg   = lane >> 4;
    const int fo   = fg * 8;
    const int pl   = wid * 16 + l15;

    for (int ci = blockIdx.x; ci < TOTALP / 64; ci += NBLOCKS) {
        const int cbase = ci * 64;
        const int P = cbase + pl;
        const int n = P & (NN - 1);
        const int b = P >> NLOG;
        const int* nip = nbr + (size_t)P * KK;
        const float* xb = x + (((size_t)b) << NLOG) * FF;

        f32x2 G2[KK][4];
        #pragma unroll
        for (int k = 0; k < KK; ++k) {
            const float* src = xb + (size_t)nip[k] * FF + fo;
            const f32x4 g0 = *(const f32x4*)(src);
            const f32x4 g1 = *(const f32x4*)(src + 4);
            G2[k][0] = f32x2{g0.x, g0.y};
            G2[k][1] = f32x2{g0.z, g0.w};
            G2[k][2] = f32x2{g1.x, g1.y};
            G2[k][3] = f32x2{g1.z, g1.w};
        }
        float vr[8];
        #pragma unroll
        for (int si = 0; si < 8; ++si) vr[si] = v[n * 8 + si];

        f32x4 acc0 = {0,0,0,0}, acc1 = {0,0,0,0}, acc2 = {0,0,0,0}, acc3 = {0,0,0,0};
        #pragma unroll
        for (int t = 0; t < KK; ++t) {
            float a[KK];
            #pragma unroll
            for (int k = 0; k < KK; ++k) {
                float s = 0.f;
                #pragma unroll
                for (int si = 0; si < 8; ++si)
                    s += vr[si] * aw[si * 81 + k * 9 + t];
                a[k] = s;
            }
            f32x2 xn2[4] = {{0,0},{0,0},{0,0},{0,0}};
            #pragma unroll
            for (int k = 0; k < KK; ++k) {
                const f32x2 ak = {a[k], a[k]};
                #pragma unroll
                for (int i = 0; i < 4; ++i) xn2[i] += G2[k][i] * ak;
            }
            s16x8 af;
            #pragma unroll
            for (int i = 0; i < 4; ++i) {
                af[2*i]   = f2bf(elu1(xn2[i].x));
                af[2*i+1] = f2bf(elu1(xn2[i].y));
            }
            const short* wrow = &Wl[l15 * WSTR + t * FF + fo];
            s16x8 b0 = *(const s16x8*)(wrow);
            s16x8 b1 = *(const s16x8*)(wrow + 16 * WSTR);
            s16x8 b2 = *(const s16x8*)(wrow + 32 * WSTR);
            s16x8 b3 = *(const s16x8*)(wrow + 48 * WSTR);
            acc0 = __builtin_amdgcn_mfma_f32_16x16x32_bf16(b0, af, acc0, 0, 0, 0);
            acc1 = __builtin_amdgcn_mfma_f32_16x16x32_bf16(b1, af, acc1, 0, 0, 0);
            acc2 = __builtin_amdgcn_mfma_f32_16x16x32_bf16(b2, af, acc2, 0, 0, 0);
            acc3 = __builtin_amdgcn_mfma_f32_16x16x32_bf16(b3, af, acc3, 0, 0, 0);
        }
        const bool zero_pt = ((P & (NN - 1)) == (NN - 1));
        float* orow = out + (size_t)P * OO + fg * 4;
        #pragma unroll
        for (int ot = 0; ot < 4; ++ot) {
            const f32x4 a = (ot == 0) ? acc0 : (ot == 1) ? acc1 : (ot == 2) ? acc2 : acc3;
            const f32x4 bv = *(const f32x4*)&BL[ot * 16 + fg * 4];
            f32x4 r;
            #pragma unroll
            for (int j = 0; j < 4; ++j)
                r[j] = zero_pt ? 0.f : elu1(a[j] + bv[j]);
            *(f32x4*)(orow + ot * 16) = r;
        }
    }
}

extern "C" void kernel_launch(void* const* d_in, const int* in_sizes, int n_in,
                              void* d_out, int out_size, void* d_ws, size_t ws_size,
                              hipStream_t stream) {
    const float* x    = (const float*)d_in[0];
    // d_in[1] = t_vertex (unused in forward)
    const int*   nbr  = (const int*)d_in[2];
    const float* v    = (const float*)d_in[3];
    const float* aw   = (const float*)d_in[4];
    const float* W    = (const float*)d_in[5];
    const float* bias = (const float*)d_in[6];
    float* out = (float*)d_out;

    const size_t xbf_bytes = (size_t)TOTALP * FF * 2;        // 33,554,432
    const size_t ra_bytes  = (size_t)NN * RA_STRIDE * 2;     //  9,437,184
    const size_t rb_bytes  = (size_t)NN * RB_STRIDE * 2;     //  1,310,720
    const size_t nb_bytes  = (size_t)TOTALP * NB_STRIDE * 2; // 10,485,760
    const size_t wb_bytes  = (size_t)OO * DD * 2;            //     36,864
    const size_t need = xbf_bytes + ra_bytes + rb_bytes + nb_bytes + wb_bytes;

    if (ws_size >= need) {
        char* base = (char*)d_ws;
        unsigned short* xbf  = (unsigned short*)base;  base += xbf_bytes;
        unsigned short* recA = (unsigned short*)base;  base += ra_bytes;
        unsigned short* recB = (unsigned short*)base;  base += rb_bytes;
        unsigned short* nb16 = (unsigned short*)base;  base += nb_bytes;
        unsigned short* wbf  = (unsigned short*)base;

        hipLaunchKernelGGL(precvt, dim3(XB + AB + NB + WB), dim3(PTHREADS), 0, stream,
                           x, xbf, v, aw, recA, recB, nbr, nb16, W, wbf);
        hipLaunchKernelGGL(paiconv_main, dim3(GRID), dim3(THREADS), 0, stream,
                           xbf, nb16, recA, recB, wbf, bias, out);
    } else {
        hipLaunchKernelGGL(paiconv_fb, dim3(NBLOCKS), dim3(PTHREADS), 0, stream,
                           x, nbr, v, aw, W, bias, out);
    }
}

// Round 21
// 148.015 us; speedup vs baseline: 1.1554x; 1.1554x over previous
//
#include <hip/hip_runtime.h>
#include <hip/hip_bf16.h>

#define NLOG 16
#define NN 65536
#define KK 9
#define FF 32
#define OO 64
#define DD 288            // K*F
#define WSTR 296          // fallback path only
#define CHUNK 128         // points per block-chunk (8 waves x 16)
#define THREADS 512
#define GRID 1024         // GRID*CHUNK = 2*NN -> vertex round-invariant
#define PTHREADS 256      // precvt block size
#define NBLOCKS 1024      // fallback grid
#define TOTALP (8 * NN)           // 524288
#define NCHUNKS (TOTALP / CHUNK)  // 4096
#define RA_STRIDE 72              // shorts/point: 9 t-rows x 8 bf16
#define RB_STRIDE 10              // shorts/point: k=8 column over t, +1 pad
#define NB_STRIDE 10              // u16 indices/point: 9 + 1 pad
#define AJW 88                    // LDS adj stride (shorts)

// fused pre-kernel block ranges (PTHREADS=256)
#define XB (TOTALP * FF / 8 / PTHREADS)  // 8192
#define AB (NN * KK / PTHREADS)          // 2304
#define NB (TOTALP / PTHREADS)           // 2048
#define WB (OO * DD / PTHREADS)          // 72

typedef float f32x4 __attribute__((ext_vector_type(4)));
typedef float f32x2 __attribute__((ext_vector_type(2)));
typedef unsigned int u32x4 __attribute__((ext_vector_type(4)));
typedef short s16x8 __attribute__((ext_vector_type(8)));
typedef short s16x4 __attribute__((ext_vector_type(4)));

static __device__ __forceinline__ short f2bf(float f) {
    union { __hip_bfloat16 h; short s; } u;
    u.h = __float2bfloat16(f);
    return u.s;
}

// exact bf16->f32
static __device__ __forceinline__ void bf2f2(unsigned int p, float& lo, float& hi) {
    union { unsigned int u; float f; } a, b;
    a.u = p << 16;
    b.u = p & 0xFFFF0000u;
    lo = a.f; hi = b.f;
}
static __device__ __forceinline__ float bf1(unsigned short s) {
    union { unsigned int u; float f; } a;
    a.u = ((unsigned int)s) << 16;
    return a.f;
}

// elu(x) = max(x, exp(min(x,0))-1)  [exp(x)-1 >= x always; drops cmp+sel]
static __device__ __forceinline__ float elu1(float x) {
    return fmaxf(x, __expf(fminf(x, 0.f)) - 1.f);
}

// ---- fused pre-kernel: xcvt | adjcvt | ncvt | wcvt(permuted) ----
__global__ __launch_bounds__(PTHREADS) void precvt(
    const float* __restrict__ x, unsigned short* __restrict__ xbf,
    const float* __restrict__ v, const float* __restrict__ aw,
    unsigned short* __restrict__ recA, unsigned short* __restrict__ recB,
    const int* __restrict__ nbr, unsigned short* __restrict__ nb16,
    const float* __restrict__ W, unsigned short* __restrict__ wbf)
{
    const int bid = blockIdx.x;
    if (bid < XB) {
        const size_t i = ((size_t)bid * PTHREADS + threadIdx.x) * 8;
        const f32x4 a = *(const f32x4*)(x + i);
        const f32x4 b = *(const f32x4*)(x + i + 4);
        s16x8 p;
        p[0] = f2bf(a.x); p[1] = f2bf(a.y); p[2] = f2bf(a.z); p[3] = f2bf(a.w);
        p[4] = f2bf(b.x); p[5] = f2bf(b.y); p[6] = f2bf(b.z); p[7] = f2bf(b.w);
        *(s16x8*)(xbf + i) = p;
    } else if (bid < XB + AB) {
        // adjacency -> packed bf16 (recA[n][t][k=0..7], recB[n][t]=k8)
        const int e = (bid - XB) * PTHREADS + threadIdx.x;   // over NN*KK
        const int n = e / KK;
        const int t = e - n * KK;
        const float* vr = v + n * 8;
        short o[8];
        float s8 = 0.f;
        #pragma unroll
        for (int k = 0; k < KK; ++k) {
            float s = 0.f;
            #pragma unroll
            for (int si = 0; si < 8; ++si)
                s += vr[si] * aw[si * 81 + k * 9 + t];
            if (k < 8) o[k] = f2bf(s); else s8 = s;
        }
        *(s16x8*)(recA + (size_t)n * RA_STRIDE + t * 8) = *(s16x8*)o;
        recB[(size_t)n * RB_STRIDE + t] = (unsigned short)f2bf(s8);
        if (t == 0) recB[(size_t)n * RB_STRIDE + 9] = 0;
    } else if (bid < XB + AB + NB) {
        const int p = (bid - XB - AB) * PTHREADS + threadIdx.x;  // over TOTALP
        const int* s = nbr + (size_t)p * KK;
        int r[KK];
        #pragma unroll
        for (int k = 0; k < KK; ++k) r[k] = s[k];
        unsigned int* d = (unsigned int*)(nb16 + (size_t)p * NB_STRIDE);
        #pragma unroll
        for (int j = 0; j < 4; ++j)
            d[j] = ((unsigned)r[2*j] & 0xFFFFu) | ((unsigned)r[2*j+1] << 16);
        d[4] = (unsigned)r[8] & 0xFFFFu;
    } else {
        // W -> bf16 lane-linear fragment layout (conflict-free wave reads)
        const int i = (bid - XB - AB - NB) * PTHREADS + threadIdx.x; // < 18432
        const int j     = i & 7;
        const int lane  = (i >> 3) & 63;
        const int tl    = i >> 9;          // t*4 + ot
        const int t     = tl >> 2;
        const int ot    = tl & 3;
        const int o     = ot * 16 + (lane & 15);
        const int d     = t * FF + (lane >> 4) * 8 + j;
        wbf[i] = (unsigned short)f2bf(W[o * DD + d]);
    }
}

// ====== main kernel (R16 = session best: timed 148.2us, main 111us) ======
// 512 thr / CHUNK 128; zero-conflict lane-linear W in LDS; AJ staged once
// (round-invariant vertices); bf16 x gather; u16 nbr; swapped MFMA; f32x4
// stores; no nt; one barrier. Ledger of failed "improvements" (do NOT redo):
//  * R17 k-outer single-unpack: xn[9][4]+g[9] live -> spills (WRITE 495MB)
//  * R18 asm-pinned G2: compiler keeps packed anyway, +5us
//  * R19 1-deep gather prefetch: VGPR 128, occ 19%, main +26us
//  * R2/R9/R10: every structure richer than this spilled at the 128 cliff
//  * R20: identical source flagged post-timing divergence once (0.61 absmax);
//    dataflow audited deterministic (full ws coverage, stream-ordered,
//    full output coverage) -> transient; R16 passed + survived rocprof replays
__global__ __launch_bounds__(THREADS, 2) void paiconv_main(
    const unsigned short* __restrict__ xbf,
    const unsigned short* __restrict__ nb16,
    const unsigned short* __restrict__ recA,
    const unsigned short* __restrict__ recB,
    const unsigned short* __restrict__ wbf,
    const float* __restrict__ bias,
    float* __restrict__ out)
{
    __shared__ short Wl[OO * DD];                // 36864 B, lane-linear layout
    __shared__ unsigned short AJ[CHUNK * AJW];   // 22528 B -> 59392 B total

    const int tid  = threadIdx.x;
    const int lane = tid & 63;
    const int wid  = tid >> 6;        // 0..7
    const int l15  = lane & 15;       // point within 16-tile (B-col)
    const int fg   = lane >> 4;       // octet group
    const int fo   = fg * 8;          // f offset (shorts)
    const int pl   = wid * 16 + l15;  // point within chunk (0..127)

    // ---- stage W (already permuted in global) linearly: conflict-free ----
    for (int e = tid; e < OO * DD / 8; e += THREADS) {
        const u32x4 r = *(const u32x4*)(wbf + (size_t)e * 8);
        *(u32x4*)(&Wl[e * 8]) = r;
    }
    // ---- stage adjacency for the block's 128 round-invariant vertices ----
    {
        const int vbase = (blockIdx.x * CHUNK) & (NN - 1);
        for (int e = tid; e < CHUNK * KK; e += THREADS) {
            const int p = e / KK;
            const int t = e - p * KK;
            const u32x4 r = *(const u32x4*)(recA + (size_t)(vbase + p) * RA_STRIDE + t * 8);
            *(u32x4*)(&AJ[p * AJW + t * 8]) = r;
        }
        if (tid < CHUNK) {
            #pragma unroll
            for (int t = 0; t < KK; ++t)
                AJ[tid * AJW + RA_STRIDE + t] =
                    recB[(size_t)(vbase + tid) * RB_STRIDE + t];
        }
    }
    __syncthreads();                    // only barrier in the kernel

    const unsigned short* ajp = &AJ[pl * AJW];
    const short* wl = &Wl[lane * 8];    // wave-linear base; imm offsets per (t,ot)

    for (int ci = blockIdx.x; ci < NCHUNKS; ci += GRID) {
        const size_t P = (size_t)ci * CHUNK + pl;
        const int b = (int)(P >> NLOG);

        // packed u16 neighbor indices (5 aligned dwords)
        const unsigned int* np = (const unsigned int*)(nb16 + P * NB_STRIDE);
        const unsigned int nw0 = np[0], nw1 = np[1], nw2 = np[2], nw3 = np[3], nw4 = np[4];
        int rows[KK];
        rows[0] = nw0 & 0xFFFF; rows[1] = nw0 >> 16;
        rows[2] = nw1 & 0xFFFF; rows[3] = nw1 >> 16;
        rows[4] = nw2 & 0xFFFF; rows[5] = nw2 >> 16;
        rows[6] = nw3 & 0xFFFF; rows[7] = nw3 >> 16;
        rows[8] = nw4 & 0xFFFF;

        // gather neighbor features (bf16): G2[k][i] = {f(fo+2i), f(fo+2i+1)}
        const unsigned short* xb = xbf + (((size_t)b) << NLOG) * FF + fo;
        f32x2 G2[KK][4];
        #pragma unroll
        for (int k = 0; k < KK; ++k) {
            const u32x4 g = *(const u32x4*)(xb + (size_t)rows[k] * FF);
            float l0,h0,l1,h1,l2,h2,l3,h3;
            bf2f2(g.x, l0, h0);
            bf2f2(g.y, l1, h1);
            bf2f2(g.z, l2, h2);
            bf2f2(g.w, l3, h3);
            G2[k][0] = f32x2{l0, h0};
            G2[k][1] = f32x2{l1, h1};
            G2[k][2] = f32x2{l2, h2};
            G2[k][3] = f32x2{l3, h3};
        }

        f32x4 acc0 = {0,0,0,0}, acc1 = {0,0,0,0}, acc2 = {0,0,0,0}, acc3 = {0,0,0,0};

        #pragma unroll 1
        for (int t = 0; t < KK; ++t) {
            float a[KK];
            {
                const u32x4 qv = *(const u32x4*)(ajp + t * 8);   // LDS, 16B
                bf2f2(qv.x, a[0], a[1]);
                bf2f2(qv.y, a[2], a[3]);
                bf2f2(qv.z, a[4], a[5]);
                bf2f2(qv.w, a[6], a[7]);
                a[8] = bf1(ajp[RA_STRIDE + t]);                  // LDS scalar
            }

            f32x2 xn2[4] = {{0,0},{0,0},{0,0},{0,0}};
            #pragma unroll
            for (int k = 0; k < KK; ++k) {
                const f32x2 ak = {a[k], a[k]};
                #pragma unroll
                for (int i = 0; i < 4; ++i) xn2[i] += G2[k][i] * ak;
            }
            s16x8 af;
            #pragma unroll
            for (int i = 0; i < 4; ++i) {
                af[2*i]   = f2bf(elu1(xn2[i].x));
                af[2*i+1] = f2bf(elu1(xn2[i].y));
            }

            // W fragments: lane-linear LDS, imm offsets -> conflict-free
            const s16x8 b0 = *(const s16x8*)(wl + (t * 4 + 0) * 512);
            const s16x8 b1 = *(const s16x8*)(wl + (t * 4 + 1) * 512);
            const s16x8 b2 = *(const s16x8*)(wl + (t * 4 + 2) * 512);
            const s16x8 b3 = *(const s16x8*)(wl + (t * 4 + 3) * 512);
            // swapped: A = W tile (row=o within 16-group), B = xn (col=point)
            acc0 = __builtin_amdgcn_mfma_f32_16x16x32_bf16(b0, af, acc0, 0, 0, 0);
            acc1 = __builtin_amdgcn_mfma_f32_16x16x32_bf16(b1, af, acc1, 0, 0, 0);
            acc2 = __builtin_amdgcn_mfma_f32_16x16x32_bf16(b2, af, acc2, 0, 0, 0);
            acc3 = __builtin_amdgcn_mfma_f32_16x16x32_bf16(b3, af, acc3, 0, 0, 0);
        }

        // epilogue: C col(l15)=point P, row(fg*4+reg)=o within 16-group ot.
        const bool zero_pt = ((P & (NN - 1)) == (NN - 1));
        float* orow = out + P * OO + fg * 4;
        #pragma unroll
        for (int ot = 0; ot < 4; ++ot) {
            const f32x4 a = (ot == 0) ? acc0 : (ot == 1) ? acc1 : (ot == 2) ? acc2 : acc3;
            const f32x4 bv = *(const f32x4*)(bias + ot * 16 + fg * 4);
            f32x4 r;
            #pragma unroll
            for (int j = 0; j < 4; ++j)
                r[j] = zero_pt ? 0.f : elu1(a[j] + bv[j]);
            *(f32x4*)(orow + ot * 16) = r;
        }
    }
}

// =============== fallback (no-ws) kernel: R8 f32 path (256 thr) ==========
__global__ __launch_bounds__(PTHREADS, 2) void paiconv_fb(
    const float* __restrict__ x,
    const int* __restrict__ nbr,
    const float* __restrict__ v,
    const float* __restrict__ aw,
    const float* __restrict__ W,
    const float* __restrict__ bias,
    float* __restrict__ out)
{
    __shared__ short Wl[OO * WSTR];
    __shared__ float BL[OO];
    const int tid = threadIdx.x;
    for (int e = tid; e < OO * DD / 4; e += PTHREADS) {
        int o = e / 72;
        int d4 = (e - o * 72) * 4;
        const f32x4 wv = *(const f32x4*)(W + o * DD + d4);
        s16x4 p;
        p.x = f2bf(wv.x); p.y = f2bf(wv.y); p.z = f2bf(wv.z); p.w = f2bf(wv.w);
        *(s16x4*)(&Wl[o * WSTR + d4]) = p;
    }
    if (tid < OO) BL[tid] = bias[tid];
    __syncthreads();

    const int lane = tid & 63;
    const int wid  = tid >> 6;
    const int l15  = lane & 15;
    const int fg   = lane >> 4;
    const int fo   = fg * 8;
    const int pl   = wid * 16 + l15;

    for (int ci = blockIdx.x; ci < TOTALP / 64; ci += NBLOCKS) {
        const int cbase = ci * 64;
        const int P = cbase + pl;
        const int n = P & (NN - 1);
        const int b = P >> NLOG;
        const int* nip = nbr + (size_t)P * KK;
        const float* xb = x + (((size_t)b) << NLOG) * FF;

        f32x2 G2[KK][4];
        #pragma unroll
        for (int k = 0; k < KK; ++k) {
            const float* src = xb + (size_t)nip[k] * FF + fo;
            const f32x4 g0 = *(const f32x4*)(src);
            const f32x4 g1 = *(const f32x4*)(src + 4);
            G2[k][0] = f32x2{g0.x, g0.y};
            G2[k][1] = f32x2{g0.z, g0.w};
            G2[k][2] = f32x2{g1.x, g1.y};
            G2[k][3] = f32x2{g1.z, g1.w};
        }
        float vr[8];
        #pragma unroll
        for (int si = 0; si < 8; ++si) vr[si] = v[n * 8 + si];

        f32x4 acc0 = {0,0,0,0}, acc1 = {0,0,0,0}, acc2 = {0,0,0,0}, acc3 = {0,0,0,0};
        #pragma unroll
        for (int t = 0; t < KK; ++t) {
            float a[KK];
            #pragma unroll
            for (int k = 0; k < KK; ++k) {
                float s = 0.f;
                #pragma unroll
                for (int si = 0; si < 8; ++si)
                    s += vr[si] * aw[si * 81 + k * 9 + t];
                a[k] = s;
            }
            f32x2 xn2[4] = {{0,0},{0,0},{0,0},{0,0}};
            #pragma unroll
            for (int k = 0; k < KK; ++k) {
                const f32x2 ak = {a[k], a[k]};
                #pragma unroll
                for (int i = 0; i < 4; ++i) xn2[i] += G2[k][i] * ak;
            }
            s16x8 af;
            #pragma unroll
            for (int i = 0; i < 4; ++i) {
                af[2*i]   = f2bf(elu1(xn2[i].x));
                af[2*i+1] = f2bf(elu1(xn2[i].y));
            }
            const short* wrow = &Wl[l15 * WSTR + t * FF + fo];
            s16x8 b0 = *(const s16x8*)(wrow);
            s16x8 b1 = *(const s16x8*)(wrow + 16 * WSTR);
            s16x8 b2 = *(const s16x8*)(wrow + 32 * WSTR);
            s16x8 b3 = *(const s16x8*)(wrow + 48 * WSTR);
            acc0 = __builtin_amdgcn_mfma_f32_16x16x32_bf16(b0, af, acc0, 0, 0, 0);
            acc1 = __builtin_amdgcn_mfma_f32_16x16x32_bf16(b1, af, acc1, 0, 0, 0);
            acc2 = __builtin_amdgcn_mfma_f32_16x16x32_bf16(b2, af, acc2, 0, 0, 0);
            acc3 = __builtin_amdgcn_mfma_f32_16x16x32_bf16(b3, af, acc3, 0, 0, 0);
        }
        const bool zero_pt = ((P & (NN - 1)) == (NN - 1));
        float* orow = out + (size_t)P * OO + fg * 4;
        #pragma unroll
        for (int ot = 0; ot < 4; ++ot) {
            const f32x4 a = (ot == 0) ? acc0 : (ot == 1) ? acc1 : (ot == 2) ? acc2 : acc3;
            const f32x4 bv = *(const f32x4*)&BL[ot * 16 + fg * 4];
            f32x4 r;
            #pragma unroll
            for (int j = 0; j < 4; ++j)
                r[j] = zero_pt ? 0.f : elu1(a[j] + bv[j]);
            *(f32x4*)(orow + ot * 16) = r;
        }
    }
}

extern "C" void kernel_launch(void* const* d_in, const int* in_sizes, int n_in,
                              void* d_out, int out_size, void* d_ws, size_t ws_size,
                              hipStream_t stream) {
    const float* x    = (const float*)d_in[0];
    // d_in[1] = t_vertex (unused in forward)
    const int*   nbr  = (const int*)d_in[2];
    const float* v    = (const float*)d_in[3];
    const float* aw   = (const float*)d_in[4];
    const float* W    = (const float*)d_in[5];
    const float* bias = (const float*)d_in[6];
    float* out = (float*)d_out;

    const size_t xbf_bytes = (size_t)TOTALP * FF * 2;        // 33,554,432
    const size_t ra_bytes  = (size_t)NN * RA_STRIDE * 2;     //  9,437,184
    const size_t rb_bytes  = (size_t)NN * RB_STRIDE * 2;     //  1,310,720
    const size_t nb_bytes  = (size_t)TOTALP * NB_STRIDE * 2; // 10,485,760
    const size_t wb_bytes  = (size_t)OO * DD * 2;            //     36,864
    const size_t need = xbf_bytes + ra_bytes + rb_bytes + nb_bytes + wb_bytes;

    if (ws_size >= need) {
        char* base = (char*)d_ws;
        unsigned short* xbf  = (unsigned short*)base;  base += xbf_bytes;
        unsigned short* recA = (unsigned short*)base;  base += ra_bytes;
        unsigned short* recB = (unsigned short*)base;  base += rb_bytes;
        unsigned short* nb16 = (unsigned short*)base;  base += nb_bytes;
        unsigned short* wbf  = (unsigned short*)base;

        hipLaunchKernelGGL(precvt, dim3(XB + AB + NB + WB), dim3(PTHREADS), 0, stream,
                           x, xbf, v, aw, recA, recB, nbr, nb16, W, wbf);
        hipLaunchKernelGGL(paiconv_main, dim3(GRID), dim3(THREADS), 0, stream,
                           xbf, nb16, recA, recB, wbf, bias, out);
    } else {
        hipLaunchKernelGGL(paiconv_fb, dim3(NBLOCKS), dim3(PTHREADS), 0, stream,
                           x, nbr, v, aw, W, bias, out);
    }
}